// Round 20
// baseline (126.426 us; speedup 1.0000x reference)
//
#include <hip/hip_runtime.h>
#include <cmath>

typedef _Float16 h16x2 __attribute__((ext_vector_type(2)));
typedef _Float16 h16x4 __attribute__((ext_vector_type(4)));
typedef _Float16 h16x8 __attribute__((ext_vector_type(8)));
typedef float    f32x4  __attribute__((ext_vector_type(4)));
typedef float    f32x16 __attribute__((ext_vector_type(16)));
typedef unsigned char      u8;
typedef unsigned int       u32;
typedef unsigned long long u64;

#define CK 2304
#define RB 584            // im2col buf row pitch in BYTES (576 fp8 + 8 pad)
#define TP 32             // pixels per fused block

// ---- compile-time level tables ----
constexpr int  eH[4]   = {100, 50, 25, 13};
constexpr int  eW[4]   = {152, 76, 38, 19};
constexpr long eFTO[4] = {0, 7782400, 9728000, 10214400};
constexpr long eLOC[4] = {0, 30400, 38000, 39900};
constexpr long eSH[4]  = {40394, 101194, 116394, 120194};
constexpr long eREF[4] = {121182, 181982, 197182, 200982};
constexpr long eAD[4]  = {201970, 7984370, 9929970, 10416370};
constexpr float eSS[4] = {64.f, 128.f, 256.f, 512.f};

__device__ __constant__ int cHW[4]  = {15200, 3800, 950, 247};
__device__ __constant__ long cFTO2[4] = {0, 7782400, 9728000, 10214400};

static __device__ __forceinline__ u32 packpair(float w) {
    _Float16 h = (_Float16)w;
    unsigned short u;
    __builtin_memcpy(&u, &h, 2);
    return (u32)u * 0x10001u;
}
static __device__ __forceinline__ h16x2 u2h(u32 v) {
    h16x2 r;
    __builtin_memcpy(&r, &v, 4);
    return r;
}

// ---------------- Kernel 0: weight prep ----------------
// wpack fp8 e4m3, pre-scaled x16, fragment-major:
//   byte i = (((mt*4+q)*36 + s)*64 + lane)*8 + u
//   oc = mt*32+(lane&31); j = s*16 + (lane>>5)*8 + u; k9 = j>>6; c = q*64+(j&63)
__global__ void __launch_bounds__(256) wconv_kernel(
    const float* __restrict__ loc_w, const float* __restrict__ shape_w,
    const float* __restrict__ adw,
    u8* __restrict__ wpack, _Float16* __restrict__ lsw)
{
    int i = blockIdx.x * 256 + threadIdx.x;
    if (i < 147456) {                 // 4 fp8 bytes per thread
        int b0 = i * 4;
        int u0 = b0 & 7;
        int lane = (b0 >> 3) & 63;
        int t = b0 >> 9;
        int s = t % 36;
        int rest = t / 36;
        int q = rest & 3;
        int mt = rest >> 2;
        int oc = mt * 32 + (lane & 31);
        float w4[4];
        #pragma unroll
        for (int j = 0; j < 4; ++j) {
            int jj = s * 16 + (lane >> 5) * 8 + u0 + j;
            int k = jj >> 6;
            int c = q * 64 + (jj & 63);
            w4[j] = adw[oc * CK + c * 9 + k] * 16.f;
        }
        int r = __builtin_amdgcn_cvt_pk_fp8_f32(w4[0], w4[1], 0, false);
        r = __builtin_amdgcn_cvt_pk_fp8_f32(w4[2], w4[3], r, true);
        ((u32*)wpack)[i] = (u32)r;
    } else if (i < 184320) {
        int i2 = i - 147456;          // < 36864
        int o = i2 / CK;
        int j = i2 - o * CK;
        int k = j >> 8, c = j & 255;
        float v = 0.f;
        if (o == 0)      v = loc_w[c * 9 + k];
        else if (o == 1) v = shape_w[c * 9 + k];
        else if (o == 2) v = shape_w[CK + c * 9 + k];
        lsw[i2] = (_Float16)v;
    }
}

// ---------------- Kernel 1: NCHW fp32 -> NHWC fp16 transpose ----------------
__global__ void __launch_bounds__(256) transpose_kernel(
    const float* __restrict__ f0, const float* __restrict__ f1,
    const float* __restrict__ f2, const float* __restrict__ f3,
    _Float16* __restrict__ ft)
{
    __shared__ float lds[64][65];
    int bid = blockIdx.x, tid = threadIdx.x;
    int lvl = (bid < 1904) ? 0 : (bid < 2384) ? 1 : (bid < 2504) ? 2 : 3;
    int base = (lvl == 0) ? 0 : (lvl == 1) ? 1904 : (lvl == 2) ? 2384 : 2504;
    int nbhw = (lvl == 0) ? 238 : (lvl == 1) ? 60 : (lvl == 2) ? 15 : 4;
    const float* f = (lvl == 0) ? f0 : (lvl == 1) ? f1 : (lvl == 2) ? f2 : f3;
    int HW = cHW[lvl];
    int b = bid - base;
    int bh = b % nbhw;
    int cg = (b / nbhw) & 3;
    int n  = b / (nbhw * 4);
    int hw0 = bh * 64;

    int pxl = tid & 63, cl = tid >> 6;
    int hwr = hw0 + pxl;
    if (hwr < HW) {
        #pragma unroll
        for (int r = 0; r < 16; ++r) {
            int c = r * 4 + cl;
            lds[c][pxl] = f[(long)(n * 256 + cg * 64 + c) * HW + hwr];
        }
    }
    __syncthreads();
    int px2 = tid >> 2, q = tid & 3;
    int hww = hw0 + px2;
    if (hww < HW) {
        _Float16* dst = ft + cFTO2[lvl] + ((long)(n * HW + hww) << 8) + cg * 64 + q * 16;
        #pragma unroll
        for (int j = 0; j < 16; j += 4) {
            h16x4 v;
            v[0] = (_Float16)lds[q * 16 + j + 0][px2];
            v[1] = (_Float16)lds[q * 16 + j + 1][px2];
            v[2] = (_Float16)lds[q * 16 + j + 2][px2];
            v[3] = (_Float16)lds[q * 16 + j + 3][px2];
            *(h16x4*)(dst + j) = v;
        }
    }
}

// ---------------- fused body (templated per level) ----------------
// 512 thr = 8 waves, phase-alternating STAGE/GEMM; fp8 deform path.
// Weight ring depth 2 (16 KB) -> 36 KB LDS total -> 4 blocks/CU (32 waves).
// Per GEMM iter: vmcnt(1) [slot d ready] -> read weights -> lgkmcnt fence
// -> issue slot d+2 (same LDS slot as d) -> 2 fp8 MFMA.
template<int LVL>
static __device__ __forceinline__ void fused_body(
    int bidl,
    u8 (*buf)[RB], u8 (*wbuf)[2][1024], float* offsm, float (*shm)[2], u32* pxm,
    const _Float16* __restrict__ ft,
    const float* __restrict__ offw,
    const u8* __restrict__ wpack,
    const _Float16* __restrict__ lsw,
    const float* __restrict__ loc_b, const float* __restrict__ shape_b,
    float* __restrict__ out)
{
    constexpr int H = eH[LVL], W = eW[LVL];
    constexpr int HW = H * W;
    constexpr int total = 2 * HW;
    const _Float16* ftl = ft + eFTO[LVL];
    float* loc_o = out + eLOC[LVL];
    float* sh_o  = out + eSH[LVL];
    float* ref_o = out + eREF[LVL];
    float* ad_o  = out + eAD[LVL];

    int tid = threadIdx.x;
    int wv = tid >> 6, lane = tid & 63;
    int nn = lane & 15, c8 = lane >> 4;
    int pix0 = bidl * TP;

    float* redB = (float*)&buf[0][0];      // [32][3][4] floats, aliases buf

    // ---- pre: pixel meta + offsets ----
    if (tid < TP) {
        int pix = pix0 + tid;
        u32 m = 0x80000000u;
        if (pix < total) {
            int n = pix / HW;
            int rem = pix - n * HW;
            int hh = rem / W;
            m = (u32)((n << 16) | (hh << 8) | (rem - hh * W));
        }
        pxm[tid] = m;
    }
    if (tid < 144) offsm[tid] = offw[tid];
    __syncthreads();

    // ---- Phase B: locshape GEMM (2 px-tiles x 4 K-quarters, f16) ----
    {
        int pxt = wv & 1, kq = wv >> 1;
        int p = pxt * 16 + nn;
        u32 pm = pxm[p];
        bool pv = !(pm >> 31);
        int ww = pm & 255, hh = (pm >> 8) & 255, n = (pm >> 16) & 1;
        f32x4 acc = {0.f, 0.f, 0.f, 0.f};
        const _Float16* ar = lsw + nn * CK + kq * 576 + c8 * 8;
        #pragma unroll 6
        for (int s = 0; s < 18; ++s) {
            int j0 = kq * 576 + s * 32;
            int k = j0 >> 8;
            int c = (j0 & 255) + c8 * 8;
            int ky = (k * 171) >> 9;
            int kx = k - ky * 3;
            int y = hh - 1 + ky, x = ww - 1 + kx;
            h16x8 b = {0, 0, 0, 0, 0, 0, 0, 0};
            if (pv && (unsigned)y < (unsigned)H && (unsigned)x < (unsigned)W)
                b = *(const h16x8*)(ftl + ((long)(n * HW + y * W + x) << 8) + c);
            h16x8 a = *(const h16x8*)(ar + s * 32);
            acc = __builtin_amdgcn_mfma_f32_16x16x32_f16(a, b, acc, 0, 0, 0);
        }
        if (c8 == 0) {
            #pragma unroll
            for (int r = 0; r < 3; ++r) redB[(p * 3 + r) * 4 + kq] = acc[r];
        }
    }
    __syncthreads();
    if (tid < 96) {
        int p = tid & 31, r = tid >> 5;
        float s = redB[(p * 3 + r) * 4 + 0] + redB[(p * 3 + r) * 4 + 1]
                + redB[(p * 3 + r) * 4 + 2] + redB[(p * 3 + r) * 4 + 3];
        u32 pm = pxm[p];
        if (!(pm >> 31)) {
            int ww = pm & 255, hh = (pm >> 8) & 255, n = (pm >> 16) & 1;
            long sp = (long)hh * W + ww;
            if (r == 0) {
                s += loc_b[0];
                loc_o[n * HW + sp] = 1.f / (1.f + expf(-s));
            } else {
                s += shape_b[r - 1];
                sh_o[(n * 2 + r - 1) * HW + sp] = s;
                ref_o[(n * 2 + r - 1) * HW + sp] = eSS[LVL] * expf(s);
                shm[p][r - 1] = s;
            }
        }
    }
    __syncthreads();

    // ---- Phases C/D: STAGE (fp8 im2col) alternating with GEMM (fp8 MFMA) ----
    int col = lane & 31, khalf = lane >> 5;
    f32x16 acc = {0,0,0,0,0,0,0,0,0,0,0,0,0,0,0,0};

    // WISSUE(q,d): DMA 1 KB (2 s-steps) of this wave's weights into ring slot
    auto WISSUE = [&](int q, int d) {
        const u8* src = wpack + (((size_t)((wv * 4 + q) * 18 + d)) << 10) + lane * 16;
        __builtin_amdgcn_global_load_lds((const void*)src, (void*)&wbuf[wv][d & 1][0], 16, 0, 0);
    };

    // STAGE(q): all 8 waves fill buf (36 items/wave); ring prefetch at top
    auto STAGE = [&](int q) {
        WISSUE(q, 0); WISSUE(q, 1);
        int it8 = lane >> 3, li8 = lane & 7;
        const _Float16* fb = ftl + q * 64 + li8 * 8;
        u32 su_word = 0, su_w00 = 0, su_w01 = 0, su_w10 = 0, su_w11 = 0;
        if (lane < 36) {
            int e = wv * 36 + lane;            // item = (p, k), e < 288
            int p = (e * 7282) >> 16;          // e/9
            int k = e - p * 9;
            u32 pm = pxm[p];
            if (!(pm >> 31)) {
                int ww = pm & 255, hh = (pm >> 8) & 255, n = (pm >> 16) & 1;
                float s0 = shm[p][0], s1 = shm[p][1];
                int gk4 = (q * 9 + k) * 4;
                float dy = offsm[gk4 + 0] * s0 + offsm[gk4 + 1] * s1;
                float dx = offsm[gk4 + 2] * s0 + offsm[gk4 + 3] * s1;
                int ky = (k * 171) >> 9;
                int kx = k - ky * 3;
                float py  = (float)(hh - 1 + ky) + dy;
                float pxf = (float)(ww - 1 + kx) + dx;
                float fy = floorf(py), fx = floorf(pxf);
                float ly = py - fy, lx = pxf - fx;
                int y0 = (int)fy, x0 = (int)fx;
                int y1 = y0 + 1, x1 = x0 + 1;
                float u00 = (1.f - ly) * (1.f - lx);
                float u01 = (1.f - ly) * lx;
                float u10 = ly * (1.f - lx);
                float u11 = ly * lx;
                bool by0 = (unsigned)y0 < (unsigned)H, by1 = (unsigned)y1 < (unsigned)H;
                bool bx0 = (unsigned)x0 < (unsigned)W, bx1 = (unsigned)x1 < (unsigned)W;
                u00 = (by0 && bx0) ? u00 : 0.f;
                u01 = (by0 && bx1) ? u01 : 0.f;
                u10 = (by1 && bx0) ? u10 : 0.f;
                u11 = (by1 && bx1) ? u11 : 0.f;
                int cy0 = min(max(y0, 0), H - 1), cy1 = min(max(y1, 0), H - 1);
                int cx0 = min(max(x0, 0), W - 1), cx1 = min(max(x1, 0), W - 1);
                int i00 = n * HW + cy0 * W + cx0;
                su_word = (u32)i00 | ((u32)(cx1 - cx0) << 30) | ((u32)(cy1 - cy0) << 31);
                su_w00 = packpair(u00); su_w01 = packpair(u01);
                su_w10 = packpair(u10); su_w11 = packpair(u11);
            }
        }
        #pragma unroll
        for (int i = 0; i < 5; ++i) {
            int item = i * 8 + it8;
            if (item >= 36) continue;
            u32 word = __shfl(su_word, item);
            u32 pw00 = __shfl(su_w00, item);
            u32 pw01 = __shfl(su_w01, item);
            u32 pw10 = __shfl(su_w10, item);
            u32 pw11 = __shfl(su_w11, item);
            int e = wv * 36 + item;
            int p = (e * 7282) >> 16;
            int k = e - p * 9;
            int i00 = word & 0x7FFF;
            int b01 = (word >> 30) & 1;
            int i10 = i00 + ((word >> 31) ? W : 0);
            h16x8 v00 = *(const h16x8*)(fb + ((long)i00 << 8));
            h16x8 v01 = *(const h16x8*)(fb + ((long)(i00 + b01) << 8));
            h16x8 v10 = *(const h16x8*)(fb + ((long)i10 << 8));
            h16x8 v11 = *(const h16x8*)(fb + ((long)(i10 + b01) << 8));
            h16x2 w00 = u2h(pw00), w01 = u2h(pw01), w10 = u2h(pw10), w11 = u2h(pw11);
            float cf[8];
            #pragma unroll
            for (int j = 0; j < 4; ++j) {
                h16x2 a00 = {v00[2*j], v00[2*j+1]};
                h16x2 a01 = {v01[2*j], v01[2*j+1]};
                h16x2 a10 = {v10[2*j], v10[2*j+1]};
                h16x2 a11 = {v11[2*j], v11[2*j+1]};
                h16x2 r = a00 * w00 + a01 * w01 + a10 * w10 + a11 * w11;
                cf[2*j]     = (float)r[0];
                cf[2*j + 1] = (float)r[1];
            }
            int lo = __builtin_amdgcn_cvt_pk_fp8_f32(cf[0], cf[1], 0, false);
            lo = __builtin_amdgcn_cvt_pk_fp8_f32(cf[2], cf[3], lo, true);
            int hi = __builtin_amdgcn_cvt_pk_fp8_f32(cf[4], cf[5], 0, false);
            hi = __builtin_amdgcn_cvt_pk_fp8_f32(cf[6], cf[7], hi, true);
            u64 r8 = ((u64)(u32)hi << 32) | (u32)lo;
            *(u64*)&buf[p][k * 64 + li8 * 8] = r8;
        }
    };

    // GEMM(q): 18 double-steps; depth-2 ring: wait slot -> read -> fence ->
    // issue next-next into same LDS slot -> 2 MFMA
    auto GEMM = [&](int q) {
        const u8* bp = &buf[col][khalf * 8];
        #pragma unroll
        for (int d = 0; d < 18; ++d) {
            if (d < 17) {
                asm volatile("s_waitcnt vmcnt(1)" ::: "memory");
            } else {
                asm volatile("s_waitcnt vmcnt(0)" ::: "memory");
            }
            const u8* wb = &wbuf[wv][d & 1][0];
            u64 w0 = *(const u64*)(wb + (lane << 3));
            u64 w1 = *(const u64*)(wb + 512 + (lane << 3));
            asm volatile("s_waitcnt lgkmcnt(0)" ::: "memory");
            if (d < 16) WISSUE(q, d + 2);
            u64 b0 = *(const u64*)(bp + (2 * d) * 16);
            u64 b1 = *(const u64*)(bp + (2 * d + 1) * 16);
            acc = __builtin_amdgcn_mfma_f32_32x32x16_fp8_fp8((long)w0, (long)b0, acc, 0, 0, 0);
            acc = __builtin_amdgcn_mfma_f32_32x32x16_fp8_fp8((long)w1, (long)b1, acc, 0, 0, 0);
        }
    };

    STAGE(0);
    __syncthreads();
    GEMM(0);
    __syncthreads();
    STAGE(1);
    __syncthreads();
    GEMM(1);
    __syncthreads();
    STAGE(2);
    __syncthreads();
    GEMM(2);
    __syncthreads();
    STAGE(3);
    __syncthreads();
    GEMM(3);

    // ---- epilogue: each wave writes its 32oc x 32px, scale 1/16 + ReLU ----
    {
        u32 pm = pxm[col];
        if (!(pm >> 31)) {
            int ww = pm & 255, hh = (pm >> 8) & 255, n = (pm >> 16) & 1;
            float* ob = ad_o + ((long)(n * 256 + wv * 32)) * HW + (long)hh * W + ww;
            #pragma unroll
            for (int reg = 0; reg < 16; ++reg) {
                int row = (reg & 3) + 8 * (reg >> 2) + 4 * khalf;
                float v = acc[reg] * 0.0625f;
                ob[(long)row * HW] = v > 0.f ? v : 0.f;
            }
        }
    }
}

__global__ void __launch_bounds__(512, 8) fused_kernel(
    const _Float16* __restrict__ ft,
    const float* __restrict__ offw,
    const u8* __restrict__ wpack,
    const _Float16* __restrict__ lsw,
    const float* __restrict__ loc_b, const float* __restrict__ shape_b,
    float* __restrict__ out)
{
    __shared__ u8 buf[TP][RB];             // 18,688 B (fp8 im2col)
    __shared__ u8 wbuf[8][2][1024];        // 16,384 B (weight DMA ring, depth 2)
    __shared__ float offsm[144];           //    576 B
    __shared__ float shm[TP][2];           //    256 B
    __shared__ u32 pxm[TP];                //    128 B  -> 36,032 B, 4 blocks/CU

    int bid0 = blockIdx.x;                 // 1264 = 8 * 158, bijective XCD swizzle
    int bid = (bid0 & 7) * 158 + (bid0 >> 3);
    if (bid < 950)
        fused_body<0>(bid,         buf, wbuf, offsm, shm, pxm, ft, offw, wpack, lsw, loc_b, shape_b, out);
    else if (bid < 1188)
        fused_body<1>(bid - 950,   buf, wbuf, offsm, shm, pxm, ft, offw, wpack, lsw, loc_b, shape_b, out);
    else if (bid < 1248)
        fused_body<2>(bid - 1188,  buf, wbuf, offsm, shm, pxm, ft, offw, wpack, lsw, loc_b, shape_b, out);
    else
        fused_body<3>(bid - 1248,  buf, wbuf, offsm, shm, pxm, ft, offw, wpack, lsw, loc_b, shape_b, out);
}

extern "C" void kernel_launch(void* const* d_in, const int* in_sizes, int n_in,
                              void* d_out, int out_size, void* d_ws, size_t ws_size,
                              hipStream_t stream)
{
    const float* f0 = (const float*)d_in[0];
    const float* f1 = (const float*)d_in[1];
    const float* f2 = (const float*)d_in[2];
    const float* f3 = (const float*)d_in[3];
    const float* loc_w    = (const float*)d_in[4];
    const float* loc_b    = (const float*)d_in[5];
    const float* shape_w  = (const float*)d_in[6];
    const float* shape_b  = (const float*)d_in[7];
    const float* offset_w = (const float*)d_in[8];
    const float* adapt_w  = (const float*)d_in[9];
    float* out = (float*)d_out;

    u8* wpack      = (u8*)d_ws;                              // 589,824 B fp8
    _Float16* lsw  = (_Float16*)((char*)d_ws + 589824);      // 36,864 halves
    _Float16* ft   = (_Float16*)((char*)d_ws + 663552);      // 10,340,864 halves

    wconv_kernel<<<720, 256, 0, stream>>>(loc_w, shape_w, adapt_w, wpack, lsw);
    transpose_kernel<<<2536, 256, 0, stream>>>(f0, f1, f2, f3, ft);
    fused_kernel<<<1264, 512, 0, stream>>>(ft, offset_w, wpack, lsw, loc_b, shape_b, out);
}

// Round 21
// 120.224 us; speedup vs baseline: 1.0516x; 1.0516x over previous
//
#include <hip/hip_runtime.h>
#include <cmath>

typedef _Float16 h16x2 __attribute__((ext_vector_type(2)));
typedef _Float16 h16x4 __attribute__((ext_vector_type(4)));
typedef _Float16 h16x8 __attribute__((ext_vector_type(8)));
typedef float    f32x4  __attribute__((ext_vector_type(4)));
typedef float    f32x16 __attribute__((ext_vector_type(16)));
typedef unsigned char      u8;
typedef unsigned int       u32;
typedef unsigned long long u64;

#define CK 2304
#define RB 584            // im2col buf row pitch in BYTES (576 fp8 + 8 pad)
#define TP 32             // pixels per fused block

// ---- compile-time level tables ----
constexpr int  eH[4]   = {100, 50, 25, 13};
constexpr int  eW[4]   = {152, 76, 38, 19};
constexpr long eFTO[4] = {0, 7782400, 9728000, 10214400};
constexpr long eLOC[4] = {0, 30400, 38000, 39900};
constexpr long eSH[4]  = {40394, 101194, 116394, 120194};
constexpr long eREF[4] = {121182, 181982, 197182, 200982};
constexpr long eAD[4]  = {201970, 7984370, 9929970, 10416370};
constexpr float eSS[4] = {64.f, 128.f, 256.f, 512.f};

__device__ __constant__ int cHW[4]  = {15200, 3800, 950, 247};
__device__ __constant__ long cFTO2[4] = {0, 7782400, 9728000, 10214400};

static __device__ __forceinline__ u32 packpair(float w) {
    _Float16 h = (_Float16)w;
    unsigned short u;
    __builtin_memcpy(&u, &h, 2);
    return (u32)u * 0x10001u;
}
static __device__ __forceinline__ h16x2 u2h(u32 v) {
    h16x2 r;
    __builtin_memcpy(&r, &v, 4);
    return r;
}

// ---------------- Kernel 0: weight prep ----------------
// wpack fp8 e4m3, pre-scaled x16, fragment-major:
//   byte i = (((mt*4+q)*36 + s)*64 + lane)*8 + u
//   oc = mt*32+(lane&31); j = s*16 + (lane>>5)*8 + u; k9 = j>>6; c = q*64+(j&63)
// lsw f16 [16][2304], j = k*256+c ; rows 0..2 = loc_w, shape_w0, shape_w1
__global__ void __launch_bounds__(256) wconv_kernel(
    const float* __restrict__ loc_w, const float* __restrict__ shape_w,
    const float* __restrict__ adw,
    u8* __restrict__ wpack, _Float16* __restrict__ lsw)
{
    int i = blockIdx.x * 256 + threadIdx.x;
    if (i < 147456) {                 // 4 fp8 bytes per thread
        int b0 = i * 4;
        int u0 = b0 & 7;
        int lane = (b0 >> 3) & 63;
        int t = b0 >> 9;
        int s = t % 36;
        int rest = t / 36;
        int q = rest & 3;
        int mt = rest >> 2;
        int oc = mt * 32 + (lane & 31);
        float w4[4];
        #pragma unroll
        for (int j = 0; j < 4; ++j) {
            int jj = s * 16 + (lane >> 5) * 8 + u0 + j;
            int k = jj >> 6;
            int c = q * 64 + (jj & 63);
            w4[j] = adw[oc * CK + c * 9 + k] * 16.f;
        }
        int r = __builtin_amdgcn_cvt_pk_fp8_f32(w4[0], w4[1], 0, false);
        r = __builtin_amdgcn_cvt_pk_fp8_f32(w4[2], w4[3], r, true);
        ((u32*)wpack)[i] = (u32)r;
    } else if (i < 184320) {
        int i2 = i - 147456;          // < 36864
        int o = i2 / CK;
        int j = i2 - o * CK;
        int k = j >> 8, c = j & 255;
        float v = 0.f;
        if (o == 0)      v = loc_w[c * 9 + k];
        else if (o == 1) v = shape_w[c * 9 + k];
        else if (o == 2) v = shape_w[CK + c * 9 + k];
        lsw[i2] = (_Float16)v;
    }
}

// ---------------- Kernel 1: NCHW fp32 -> NHWC fp16 transpose ----------------
__global__ void __launch_bounds__(256) transpose_kernel(
    const float* __restrict__ f0, const float* __restrict__ f1,
    const float* __restrict__ f2, const float* __restrict__ f3,
    _Float16* __restrict__ ft)
{
    __shared__ float lds[64][65];
    int bid = blockIdx.x, tid = threadIdx.x;
    int lvl = (bid < 1904) ? 0 : (bid < 2384) ? 1 : (bid < 2504) ? 2 : 3;
    int base = (lvl == 0) ? 0 : (lvl == 1) ? 1904 : (lvl == 2) ? 2384 : 2504;
    int nbhw = (lvl == 0) ? 238 : (lvl == 1) ? 60 : (lvl == 2) ? 15 : 4;
    const float* f = (lvl == 0) ? f0 : (lvl == 1) ? f1 : (lvl == 2) ? f2 : f3;
    int HW = cHW[lvl];
    int b = bid - base;
    int bh = b % nbhw;
    int cg = (b / nbhw) & 3;
    int n  = b / (nbhw * 4);
    int hw0 = bh * 64;

    int pxl = tid & 63, cl = tid >> 6;
    int hwr = hw0 + pxl;
    if (hwr < HW) {
        #pragma unroll
        for (int r = 0; r < 16; ++r) {
            int c = r * 4 + cl;
            lds[c][pxl] = f[(long)(n * 256 + cg * 64 + c) * HW + hwr];
        }
    }
    __syncthreads();
    int px2 = tid >> 2, q = tid & 3;
    int hww = hw0 + px2;
    if (hww < HW) {
        _Float16* dst = ft + cFTO2[lvl] + ((long)(n * HW + hww) << 8) + cg * 64 + q * 16;
        #pragma unroll
        for (int j = 0; j < 16; j += 4) {
            h16x4 v;
            v[0] = (_Float16)lds[q * 16 + j + 0][px2];
            v[1] = (_Float16)lds[q * 16 + j + 1][px2];
            v[2] = (_Float16)lds[q * 16 + j + 2][px2];
            v[3] = (_Float16)lds[q * 16 + j + 3][px2];
            *(h16x4*)(dst + j) = v;
        }
    }
}

// ---------------- fused body (templated per level) ----------------
// 512 thr = 8 waves, phase-alternating STAGE/GEMM; fp8 deform path.
// Weights stream through a per-wave LDS ring (wbuf) via global_load_lds:
// 1 KB DMA covers 2 s-steps; 3 slots issued ahead; counted vmcnt waits.
template<int LVL>
static __device__ __forceinline__ void fused_body(
    int bidl,
    u8 (*buf)[RB], u8 (*wbuf)[4][1024], float* offsm, float (*shm)[2], u32* pxm,
    const _Float16* __restrict__ ft,
    const float* __restrict__ offw,
    const u8* __restrict__ wpack,
    const _Float16* __restrict__ lsw,
    const float* __restrict__ loc_b, const float* __restrict__ shape_b,
    float* __restrict__ out)
{
    constexpr int H = eH[LVL], W = eW[LVL];
    constexpr int HW = H * W;
    constexpr int total = 2 * HW;
    const _Float16* ftl = ft + eFTO[LVL];
    float* loc_o = out + eLOC[LVL];
    float* sh_o  = out + eSH[LVL];
    float* ref_o = out + eREF[LVL];
    float* ad_o  = out + eAD[LVL];

    int tid = threadIdx.x;
    int wv = tid >> 6, lane = tid & 63;
    int nn = lane & 15, c8 = lane >> 4;
    int pix0 = bidl * TP;

    float* redB = (float*)&buf[0][0];      // [32][3][4] floats, aliases buf

    // ---- pre: pixel meta + offsets ----
    if (tid < TP) {
        int pix = pix0 + tid;
        u32 m = 0x80000000u;
        if (pix < total) {
            int n = pix / HW;
            int rem = pix - n * HW;
            int hh = rem / W;
            m = (u32)((n << 16) | (hh << 8) | (rem - hh * W));
        }
        pxm[tid] = m;
    }
    if (tid < 144) offsm[tid] = offw[tid];
    __syncthreads();

    // ---- Phase B: locshape GEMM (2 px-tiles x 4 K-quarters, f16) ----
    {
        int pxt = wv & 1, kq = wv >> 1;
        int p = pxt * 16 + nn;
        u32 pm = pxm[p];
        bool pv = !(pm >> 31);
        int ww = pm & 255, hh = (pm >> 8) & 255, n = (pm >> 16) & 1;
        f32x4 acc = {0.f, 0.f, 0.f, 0.f};
        const _Float16* ar = lsw + nn * CK + kq * 576 + c8 * 8;
        #pragma unroll 6
        for (int s = 0; s < 18; ++s) {
            int j0 = kq * 576 + s * 32;
            int k = j0 >> 8;
            int c = (j0 & 255) + c8 * 8;
            int ky = (k * 171) >> 9;
            int kx = k - ky * 3;
            int y = hh - 1 + ky, x = ww - 1 + kx;
            h16x8 b = {0, 0, 0, 0, 0, 0, 0, 0};
            if (pv && (unsigned)y < (unsigned)H && (unsigned)x < (unsigned)W)
                b = *(const h16x8*)(ftl + ((long)(n * HW + y * W + x) << 8) + c);
            h16x8 a = *(const h16x8*)(ar + s * 32);
            acc = __builtin_amdgcn_mfma_f32_16x16x32_f16(a, b, acc, 0, 0, 0);
        }
        if (c8 == 0) {
            #pragma unroll
            for (int r = 0; r < 3; ++r) redB[(p * 3 + r) * 4 + kq] = acc[r];
        }
    }
    __syncthreads();
    if (tid < 96) {
        int p = tid & 31, r = tid >> 5;
        float s = redB[(p * 3 + r) * 4 + 0] + redB[(p * 3 + r) * 4 + 1]
                + redB[(p * 3 + r) * 4 + 2] + redB[(p * 3 + r) * 4 + 3];
        u32 pm = pxm[p];
        if (!(pm >> 31)) {
            int ww = pm & 255, hh = (pm >> 8) & 255, n = (pm >> 16) & 1;
            long sp = (long)hh * W + ww;
            if (r == 0) {
                s += loc_b[0];
                loc_o[n * HW + sp] = 1.f / (1.f + expf(-s));
            } else {
                s += shape_b[r - 1];
                sh_o[(n * 2 + r - 1) * HW + sp] = s;
                ref_o[(n * 2 + r - 1) * HW + sp] = eSS[LVL] * expf(s);
                shm[p][r - 1] = s;
            }
        }
    }
    __syncthreads();

    // ---- Phases C/D: STAGE (fp8 im2col) alternating with GEMM (fp8 MFMA) ----
    int col = lane & 31, khalf = lane >> 5;
    f32x16 acc = {0,0,0,0,0,0,0,0,0,0,0,0,0,0,0,0};

    // WISSUE(q,d): DMA 1 KB (2 s-steps) of this wave's weights into wbuf slot
    auto WISSUE = [&](int q, int d) {
        const u8* src = wpack + (((size_t)((wv * 4 + q) * 18 + d)) << 10) + lane * 16;
        __builtin_amdgcn_global_load_lds((const void*)src, (void*)&wbuf[wv][d & 3][0], 16, 0, 0);
    };

    // STAGE(q): all 8 waves fill buf (36 items/wave); weight prefetch at top
    auto STAGE = [&](int q) {
        WISSUE(q, 0); WISSUE(q, 1); WISSUE(q, 2);
        int it8 = lane >> 3, li8 = lane & 7;
        const _Float16* fb = ftl + q * 64 + li8 * 8;
        u32 su_word = 0, su_w00 = 0, su_w01 = 0, su_w10 = 0, su_w11 = 0;
        if (lane < 36) {
            int e = wv * 36 + lane;            // item = (p, k), e < 288
            int p = (e * 7282) >> 16;          // e/9
            int k = e - p * 9;
            u32 pm = pxm[p];
            if (!(pm >> 31)) {
                int ww = pm & 255, hh = (pm >> 8) & 255, n = (pm >> 16) & 1;
                float s0 = shm[p][0], s1 = shm[p][1];
                int gk4 = (q * 9 + k) * 4;
                float dy = offsm[gk4 + 0] * s0 + offsm[gk4 + 1] * s1;
                float dx = offsm[gk4 + 2] * s0 + offsm[gk4 + 3] * s1;
                int ky = (k * 171) >> 9;
                int kx = k - ky * 3;
                float py  = (float)(hh - 1 + ky) + dy;
                float pxf = (float)(ww - 1 + kx) + dx;
                float fy = floorf(py), fx = floorf(pxf);
                float ly = py - fy, lx = pxf - fx;
                int y0 = (int)fy, x0 = (int)fx;
                int y1 = y0 + 1, x1 = x0 + 1;
                float u00 = (1.f - ly) * (1.f - lx);
                float u01 = (1.f - ly) * lx;
                float u10 = ly * (1.f - lx);
                float u11 = ly * lx;
                bool by0 = (unsigned)y0 < (unsigned)H, by1 = (unsigned)y1 < (unsigned)H;
                bool bx0 = (unsigned)x0 < (unsigned)W, bx1 = (unsigned)x1 < (unsigned)W;
                u00 = (by0 && bx0) ? u00 : 0.f;
                u01 = (by0 && bx1) ? u01 : 0.f;
                u10 = (by1 && bx0) ? u10 : 0.f;
                u11 = (by1 && bx1) ? u11 : 0.f;
                int cy0 = min(max(y0, 0), H - 1), cy1 = min(max(y1, 0), H - 1);
                int cx0 = min(max(x0, 0), W - 1), cx1 = min(max(x1, 0), W - 1);
                int i00 = n * HW + cy0 * W + cx0;
                su_word = (u32)i00 | ((u32)(cx1 - cx0) << 30) | ((u32)(cy1 - cy0) << 31);
                su_w00 = packpair(u00); su_w01 = packpair(u01);
                su_w10 = packpair(u10); su_w11 = packpair(u11);
            }
        }
        #pragma unroll
        for (int i = 0; i < 5; ++i) {
            int item = i * 8 + it8;
            if (item >= 36) continue;
            u32 word = __shfl(su_word, item);
            u32 pw00 = __shfl(su_w00, item);
            u32 pw01 = __shfl(su_w01, item);
            u32 pw10 = __shfl(su_w10, item);
            u32 pw11 = __shfl(su_w11, item);
            int e = wv * 36 + item;
            int p = (e * 7282) >> 16;
            int k = e - p * 9;
            int i00 = word & 0x7FFF;
            int b01 = (word >> 30) & 1;
            int i10 = i00 + ((word >> 31) ? W : 0);
            h16x8 v00 = *(const h16x8*)(fb + ((long)i00 << 8));
            h16x8 v01 = *(const h16x8*)(fb + ((long)(i00 + b01) << 8));
            h16x8 v10 = *(const h16x8*)(fb + ((long)i10 << 8));
            h16x8 v11 = *(const h16x8*)(fb + ((long)(i10 + b01) << 8));
            h16x2 w00 = u2h(pw00), w01 = u2h(pw01), w10 = u2h(pw10), w11 = u2h(pw11);
            float cf[8];
            #pragma unroll
            for (int j = 0; j < 4; ++j) {
                h16x2 a00 = {v00[2*j], v00[2*j+1]};
                h16x2 a01 = {v01[2*j], v01[2*j+1]};
                h16x2 a10 = {v10[2*j], v10[2*j+1]};
                h16x2 a11 = {v11[2*j], v11[2*j+1]};
                h16x2 r = a00 * w00 + a01 * w01 + a10 * w10 + a11 * w11;
                cf[2*j]     = (float)r[0];
                cf[2*j + 1] = (float)r[1];
            }
            int lo = __builtin_amdgcn_cvt_pk_fp8_f32(cf[0], cf[1], 0, false);
            lo = __builtin_amdgcn_cvt_pk_fp8_f32(cf[2], cf[3], lo, true);
            int hi = __builtin_amdgcn_cvt_pk_fp8_f32(cf[4], cf[5], 0, false);
            hi = __builtin_amdgcn_cvt_pk_fp8_f32(cf[6], cf[7], hi, true);
            u64 r8 = ((u64)(u32)hi << 32) | (u32)lo;
            *(u64*)&buf[p][k * 64 + li8 * 8] = r8;
        }
    };

    // GEMM(q): 18 double-steps; weights from wbuf ring (DMA 3 ahead), b from buf
    auto GEMM = [&](int q) {
        const u8* bp = &buf[col][khalf * 8];
        #pragma unroll
        for (int d = 0; d < 18; ++d) {
            if (d < 15) {
                WISSUE(q, d + 3);
                asm volatile("s_waitcnt vmcnt(3)" ::: "memory");
            } else if (d == 15) {
                asm volatile("s_waitcnt vmcnt(2)" ::: "memory");
            } else if (d == 16) {
                asm volatile("s_waitcnt vmcnt(1)" ::: "memory");
            } else {
                asm volatile("s_waitcnt vmcnt(0)" ::: "memory");
            }
            const u8* wb = &wbuf[wv][d & 3][0];
            u64 w0 = *(const u64*)(wb + (lane << 3));
            u64 w1 = *(const u64*)(wb + 512 + (lane << 3));
            u64 b0 = *(const u64*)(bp + (2 * d) * 16);
            u64 b1 = *(const u64*)(bp + (2 * d + 1) * 16);
            acc = __builtin_amdgcn_mfma_f32_32x32x16_fp8_fp8((long)w0, (long)b0, acc, 0, 0, 0);
            acc = __builtin_amdgcn_mfma_f32_32x32x16_fp8_fp8((long)w1, (long)b1, acc, 0, 0, 0);
        }
    };

    STAGE(0);
    __syncthreads();
    GEMM(0);
    __syncthreads();
    STAGE(1);
    __syncthreads();
    GEMM(1);
    __syncthreads();
    STAGE(2);
    __syncthreads();
    GEMM(2);
    __syncthreads();
    STAGE(3);
    __syncthreads();
    GEMM(3);

    // ---- epilogue: each wave writes its 32oc x 32px, scale 1/16 + ReLU ----
    {
        u32 pm = pxm[col];
        if (!(pm >> 31)) {
            int ww = pm & 255, hh = (pm >> 8) & 255, n = (pm >> 16) & 1;
            float* ob = ad_o + ((long)(n * 256 + wv * 32)) * HW + (long)hh * W + ww;
            #pragma unroll
            for (int reg = 0; reg < 16; ++reg) {
                int row = (reg & 3) + 8 * (reg >> 2) + 4 * khalf;
                float v = acc[reg] * 0.0625f;
                ob[(long)row * HW] = v > 0.f ? v : 0.f;
            }
        }
    }
}

__global__ void __launch_bounds__(512, 4) fused_kernel(
    const _Float16* __restrict__ ft,
    const float* __restrict__ offw,
    const u8* __restrict__ wpack,
    const _Float16* __restrict__ lsw,
    const float* __restrict__ loc_b, const float* __restrict__ shape_b,
    float* __restrict__ out)
{
    __shared__ u8 buf[TP][RB];             // 18,688 B (fp8 im2col)
    __shared__ u8 wbuf[8][4][1024];        // 32,768 B (weight DMA ring)
    __shared__ float offsm[144];           //    576 B
    __shared__ float shm[TP][2];           //    256 B
    __shared__ u32 pxm[TP];                //    128 B  -> 52,416 B, 3 blocks/CU

    int bid0 = blockIdx.x;                 // 1264 = 8 * 158, bijective XCD swizzle
    int bid = (bid0 & 7) * 158 + (bid0 >> 3);
    if (bid < 950)
        fused_body<0>(bid,         buf, wbuf, offsm, shm, pxm, ft, offw, wpack, lsw, loc_b, shape_b, out);
    else if (bid < 1188)
        fused_body<1>(bid - 950,   buf, wbuf, offsm, shm, pxm, ft, offw, wpack, lsw, loc_b, shape_b, out);
    else if (bid < 1248)
        fused_body<2>(bid - 1188,  buf, wbuf, offsm, shm, pxm, ft, offw, wpack, lsw, loc_b, shape_b, out);
    else
        fused_body<3>(bid - 1248,  buf, wbuf, offsm, shm, pxm, ft, offw, wpack, lsw, loc_b, shape_b, out);
}

extern "C" void kernel_launch(void* const* d_in, const int* in_sizes, int n_in,
                              void* d_out, int out_size, void* d_ws, size_t ws_size,
                              hipStream_t stream)
{
    const float* f0 = (const float*)d_in[0];
    const float* f1 = (const float*)d_in[1];
    const float* f2 = (const float*)d_in[2];
    const float* f3 = (const float*)d_in[3];
    const float* loc_w    = (const float*)d_in[4];
    const float* loc_b    = (const float*)d_in[5];
    const float* shape_w  = (const float*)d_in[6];
    const float* shape_b  = (const float*)d_in[7];
    const float* offset_w = (const float*)d_in[8];
    const float* adapt_w  = (const float*)d_in[9];
    float* out = (float*)d_out;

    u8* wpack      = (u8*)d_ws;                              // 589,824 B fp8
    _Float16* lsw  = (_Float16*)((char*)d_ws + 589824);      // 36,864 halves
    _Float16* ft   = (_Float16*)((char*)d_ws + 663552);      // 10,340,864 halves

    wconv_kernel<<<720, 256, 0, stream>>>(loc_w, shape_w, adapt_w, wpack, lsw);
    transpose_kernel<<<2536, 256, 0, stream>>>(f0, f1, f2, f3, ft);
    fused_kernel<<<1264, 512, 0, stream>>>(ft, offset_w, wpack, lsw, loc_b, shape_b, out);
}